// Round 13
// baseline (273.092 us; speedup 1.0000x reference)
//
#include <hip/hip_runtime.h>

#define LN2F 0.6931471805599453f

// Problem constants (from setup_inputs: B=8, T=128, U=64, V=1024)
#define B_   8
#define T_   128
#define U_   64
#define U1_  65
#define V_   1024
#define ROWS_ (B_*T_*U1_)       // 66560
#define NDIAG_ 224              // diag index g=t+u in [0,192]; padded
#define DS_    66               // float2 slots per diagonal (i = u in [1,64] used)
#define PACKB_ (NDIAG_*DS_)     // float2 per batch
#define COL0N_ 224
#define NWAVES_ 8192            // persistent k1: 2048 blocks * 4 waves (8/CU, 32 waves/CU)
#define K1_BLOCKS_ 2048
#define REP_ 24                 // DIAGNOSTIC: k2 repetitions (surfaces in rocprof top-5)

typedef float f32x4 __attribute__((ext_vector_type(4)));

// lane l <- lane l-1; lane 0 <- 0.0 (DPP wave_shr:1, bound_ctrl=1). One VALU op.
__device__ __forceinline__ float shr1_f32(float x) {
  return __int_as_float(__builtin_amdgcn_update_dpp(
      0, __float_as_int(x), 0x138, 0xf, 0xf, true));
}

// Full-wave float max via DPP (VALU pipe only; no DS). Invalid-source lanes
// keep old=x (max identity). Result uniform via readlane 63.
__device__ __forceinline__ float wave_fmax_dpp(float x) {
#define DPPM_(ctrl) { int t_ = __builtin_amdgcn_update_dpp(                  \
      __float_as_int(x), __float_as_int(x), (ctrl), 0xf, 0xf, false);        \
    x = fmaxf(x, __int_as_float(t_)); }
  DPPM_(0x111) DPPM_(0x112) DPPM_(0x114) DPPM_(0x118)   // row_shr 1,2,4,8
  DPPM_(0x142) DPPM_(0x143)                             // row_bcast 15,31
#undef DPPM_
  return __int_as_float(__builtin_amdgcn_readlane(__float_as_int(x), 63));
}

// Full-wave float sum via DPP (0-fill on invalid lanes = add identity).
__device__ __forceinline__ float wave_fsum_dpp(float x) {
#define DPPA_(ctrl) { int t_ = __builtin_amdgcn_update_dpp(                  \
      0, __float_as_int(x), (ctrl), 0xf, 0xf, true);                         \
    x += __int_as_float(t_); }
  DPPA_(0x111) DPPA_(0x112) DPPA_(0x114) DPPA_(0x118)
  DPPA_(0x142) DPPA_(0x143)
#undef DPPA_
  return __int_as_float(__builtin_amdgcn_readlane(__float_as_int(x), 63));
}

// wave-max of biased f32 exponents of (a, i0) via DPP reduce (R10-validated).
__device__ __forceinline__ int wave_max_bexp(float a, float i0) {
  int e  = (int)((__float_as_uint(a)  >> 23) & 0xffu);
  int e2 = (int)((__float_as_uint(i0) >> 23) & 0xffu);
  e = max(e, e2);
  int t;
  t = __builtin_amdgcn_update_dpp(e, e, 0x111, 0xf, 0xf, false); e = max(e, t);
  t = __builtin_amdgcn_update_dpp(e, e, 0x112, 0xf, 0xf, false); e = max(e, t);
  t = __builtin_amdgcn_update_dpp(e, e, 0x114, 0xf, 0xf, false); e = max(e, t);
  t = __builtin_amdgcn_update_dpp(e, e, 0x118, 0xf, 0xf, false); e = max(e, t);
  t = __builtin_amdgcn_update_dpp(e, e, 0x142, 0xf, 0xf, false); e = max(e, t);
  t = __builtin_amdgcn_update_dpp(e, e, 0x143, 0xf, 0xf, false); e = max(e, t);
  return __builtin_amdgcn_readlane(e, 63);
}

// ---------------------------------------------------------------------------
// K1: R11's persistent-grid wave-per-row softmax (2048 blocks, 32 waves/CU),
//     but with DPP reductions replacing ds_swizzle shuffles (DS-pipe relief).
//     Emits LINEAR probs in diagonal-major layout:
//       pk[b][t+u][u] = (.x = pll[t][u-1], .y = pbl[t][u])
//       col0[b][t+1]  = (.x = pbl[t][0],   .y = pll[t][0])
// ---------------------------------------------------------------------------
__global__ __launch_bounds__(256) void k1_linsoftmax(
    const float* __restrict__ acts, const int* __restrict__ labels,
    const int* __restrict__ label_lens,
    float2* __restrict__ pack, float2* __restrict__ col0, int* __restrict__ cnt) {
  const int lane = threadIdx.x & 63;
  const int wid  = blockIdx.x * 4 + (threadIdx.x >> 6);
  if (wid == 0 && lane == 0) *cnt = 0;             // k2's completion counter

  for (int row = wid; row < ROWS_; row += NWAVES_) {
    const int b   = row / (T_ * U1_);
    const int rem = row - b * (T_ * U1_);
    const int t   = rem / U1_;
    const int u   = rem - t * U1_;
    const float* __restrict__ p = acts + (size_t)row * V_;

    // hoisted label-path loads (lane 0 only)
    int ll_ = 0; float labv = 0.0f;
    if (lane == 0 && u < U_) {
      ll_  = label_lens[b];
      labv = p[labels[b * U_ + u]];                // in [1, V)
    }

    f32x4 v0 = *(const f32x4*)(p +   0 + lane * 4);
    f32x4 v1 = *(const f32x4*)(p + 256 + lane * 4);
    f32x4 v2 = *(const f32x4*)(p + 512 + lane * 4);
    f32x4 v3 = *(const f32x4*)(p + 768 + lane * 4);

    float ml = fmaxf(fmaxf(fmaxf(v0.x, v0.y), fmaxf(v0.z, v0.w)),
               fmaxf(fmaxf(fmaxf(v1.x, v1.y), fmaxf(v1.z, v1.w)),
               fmaxf(fmaxf(fmaxf(v2.x, v2.y), fmaxf(v2.z, v2.w)),
                     fmaxf(fmaxf(v3.x, v3.y), fmaxf(v3.z, v3.w)))));
    float m = wave_fmax_dpp(ml);                   // uniform scalar (SGPR)

    float e00 = __expf(v0.x - m);                  // lane 0 holds exp(p[0]-m)
    float sl = e00          + __expf(v0.y - m) + __expf(v0.z - m) + __expf(v0.w - m)
             + __expf(v1.x - m) + __expf(v1.y - m) + __expf(v1.z - m) + __expf(v1.w - m)
             + __expf(v2.x - m) + __expf(v2.y - m) + __expf(v2.z - m) + __expf(v2.w - m)
             + __expf(v3.x - m) + __expf(v3.y - m) + __expf(v3.z - m) + __expf(v3.w - m);
    float s = wave_fsum_dpp(sl);                   // uniform scalar

    if (lane == 0) {
      float rs = 1.0f / s;
      float pb = e00 * rs;                         // linear blank prob
      float2* pk = pack + (size_t)b * PACKB_;
      if (u == 0) {
        float pl0 = __expf(labv - m) * rs;         // u=0 < ll_ always (ll_ >= 32)
        col0[b * COL0N_ + (t + 1)] = make_float2(pb, pl0);
        pk[(size_t)(t + 1) * DS_ + 1].x = pl0;
      } else {
        pk[(size_t)(t + u) * DS_ + u].y = pb;
        if (u < U_) {
          float plv = (u < ll_) ? (__expf(labv - m) * rs) : 0.0f;
          pk[(size_t)(t + u + 1) * DS_ + (u + 1)].x = plv;
        }
      }
    }
  }
}

// ---------------------------------------------------------------------------
// K2: R11's f32 probability-domain diagonal DP (8 blocks x 64), repeated
//     REP_ times (idempotent; keep-alives defeat LICM) so its true cost and
//     counters surface in rocprof top-5. k2_true = row_dur / REP_.
// ---------------------------------------------------------------------------
__global__ __launch_bounds__(64) void k2_alpha(
    const float2* __restrict__ pack, const float2* __restrict__ col0,
    const int* __restrict__ act_lens, const int* __restrict__ label_lens,
    float* __restrict__ costs, int* __restrict__ cnt, float* __restrict__ out) {
  const int b  = (int)blockIdx.x;
  const int l  = (int)threadIdx.x;                 // 0..63
  const int tl = act_lens[b] - 1;                  // in [63,127]
  const int ll = label_lens[b];                    // in [32,64]
  const int u  = l + 1;
  const int tcap = (u == ll) ? tl : 0x7fffffff;    // capture when t_ == tcap

  const float2* __restrict__ pku = pack + (size_t)b * PACKB_ + u;   // +DS_ per diag
  const float2* __restrict__ c0  = col0 + (size_t)b * COL0N_;

#define LOADP(P, C, DB) do {                                             \
    const float2* q_ = pku + (size_t)(DB) * DS_;                         \
    _Pragma("unroll")                                                    \
    for (int j = 0; j < 16; ++j) (P)[j] = q_[(size_t)j * DS_];           \
    _Pragma("unroll")                                                    \
    for (int j = 0; j < 16; ++j) {                                       \
      float2 cv_ = c0[(DB) + j];                                         \
      bool ok_ = ((DB) + j) <= T_;            /* dc-1 in [0,127] */      \
      (C)[j].x = ok_ ? cv_.x : 0.0f;                                     \
      (C)[j].y = ok_ ? cv_.y : 0.0f;                                     \
    }                                                                    \
  } while (0)

#define RENORM() do {                                                    \
    int eS_ = wave_max_bexp(a, i0);                                      \
    int sh_ = min(167 - eS_, 126);     /* target biased exp 167 = 2^40 */\
    S += sh_;                                                            \
    float sc_ = ldexpf(1.0f, sh_);                                       \
    a *= sc_; i0 *= sc_;                                                 \
  } while (0)

#define COMPUTE8(P, C, JO) do {                                          \
    _Pragma("unroll")                                                    \
    for (int jj = 0; jj < 8; ++jj) {                                     \
      const int j = (JO) + jj;                                           \
      t_ += 1;                                                           \
      float shin = shr1_f32(a);                                          \
      float inj  = i0 * (C)[j].y;                                        \
      float anew = fmaf(a, pbc, fmaf(shin, (P)[j].x, inj));              \
      bool valid = ((unsigned)t_ < (unsigned)T_);                        \
      a = valid ? anew : 0.0f;            /* kills pad garbage/NaN */    \
      bool cap = (t_ == tcap);                                           \
      fin  = cap ? a : fin;                                              \
      Ecap = cap ? S : Ecap;                                             \
      i0 *= (C)[j].x;                                                    \
      pbc = (P)[j].y;                                                    \
    }                                                                    \
  } while (0)

  #pragma unroll 1
  for (int rep = 0; rep < REP_; ++rep) {
    float a = 0.0f;
    float i0 = (l == 0) ? 1.0f : 0.0f;             // alpha0 side-chain (lane 0)
    asm volatile("" : "+v"(a), "+v"(i0));          // defeat LICM across reps
    float fin = 0.0f, pbc = 0.0f;
    int   S = 0, Ecap = 0;
    int   t_ = -u;                                 // becomes dc-u after ++ in step

    float2 pA[16], pB[16], cA[16], cB[16];

    LOADP(pA, cA, 1);                              // block 0: dc = 1..16
    #pragma unroll 1
    for (int it = 0; it < 12; it += 2) {           // 6 iters x 32 steps = 192
      LOADP(pB, cB, 16 * it + 17);                 // odd block
      if (it > 0) RENORM();
      COMPUTE8(pA, cA, 0);
      RENORM();
      COMPUTE8(pA, cA, 8);
      if (it < 10) LOADP(pA, cA, 16 * it + 33);    // next even block
      RENORM();
      COMPUTE8(pB, cB, 0);
      RENORM();
      COMPUTE8(pB, cB, 8);
    }

    if (u == ll) {                                 // exactly one lane (ll in [32,64])
      float pblast = pack[(size_t)b * PACKB_ + (size_t)(tl + ll) * DS_ + ll].y;
      float lg = __log2f(fin) - (float)Ecap + __log2f(pblast);
      costs[b] = -lg * LN2F;
    }
  }
#undef LOADP
#undef RENORM
#undef COMPUTE8

  // last block to arrive sums the 8 costs (deterministic: single writer)
  __threadfence();
  if (l == 0) {
    int old = atomicAdd(cnt, 1);
    if (old == B_ - 1) {
      __threadfence();
      volatile const float* vc = costs;
      float s = 0.0f;
      #pragma unroll
      for (int i = 0; i < B_; ++i) s += vc[i];
      out[0] = s;
    }
  }
}

extern "C" void kernel_launch(void* const* d_in, const int* in_sizes, int n_in,
                              void* d_out, int out_size, void* d_ws, size_t ws_size,
                              hipStream_t stream) {
  const float* acts       = (const float*)d_in[0];
  const int*   labels     = (const int*)d_in[1];
  const int*   act_lens   = (const int*)d_in[2];
  const int*   label_lens = (const int*)d_in[3];

  float2* pack  = (float2*)d_ws;                     // B * 224*66 float2 = 946 KB
  float2* col0  = pack + (size_t)B_ * PACKB_;        // B * 224 float2
  float*  costs = (float*)(col0 + (size_t)B_ * COL0N_);
  int*    cnt   = (int*)(costs + B_);                // 1 int

  k1_linsoftmax<<<K1_BLOCKS_, 256, 0, stream>>>(acts, labels, label_lens, pack, col0, cnt);
  k2_alpha<<<B_, 64, 0, stream>>>(pack, col0, act_lens, label_lens, costs, cnt, (float*)d_out);
}

// Round 14
// 61.995 us; speedup vs baseline: 4.4050x; 4.4050x over previous
//
#include <hip/hip_runtime.h>

#define LN2F 0.6931471805599453f

// Problem constants (from setup_inputs: B=8, T=128, U=64, V=1024)
#define B_   8
#define T_   128
#define U_   64
#define U1_  65
#define V_   1024
#define ROWS_ (B_*T_*U1_)       // 66560
#define NDIAG_ 224              // diag index g=t+u in [0,192]; padded (DP reads to 208)
#define DS_    66               // float2 slots per diagonal (i = u in [1,64] used)
#define PACKB_ (NDIAG_*DS_)     // float2 per batch = 14784
#define COL0N_ 224
#define NWAVES_ 8192            // persistent k1: 2048 blocks * 4 waves (8/CU, 32 waves/CU)
#define K1_BLOCKS_ 2048

typedef float f32x4 __attribute__((ext_vector_type(4)));

// lane l <- lane l-1; lane 0 <- 0.0 (DPP wave_shr:1, bound_ctrl=1). One VALU op.
__device__ __forceinline__ float shr1_f32(float x) {
  return __int_as_float(__builtin_amdgcn_update_dpp(
      0, __float_as_int(x), 0x138, 0xf, 0xf, true));
}

// Full-wave float max via DPP (VALU pipe only; no DS traffic).
__device__ __forceinline__ float wave_fmax_dpp(float x) {
#define DPPM_(ctrl) { int t_ = __builtin_amdgcn_update_dpp(                  \
      __float_as_int(x), __float_as_int(x), (ctrl), 0xf, 0xf, false);        \
    x = fmaxf(x, __int_as_float(t_)); }
  DPPM_(0x111) DPPM_(0x112) DPPM_(0x114) DPPM_(0x118)   // row_shr 1,2,4,8
  DPPM_(0x142) DPPM_(0x143)                             // row_bcast 15,31
#undef DPPM_
  return __int_as_float(__builtin_amdgcn_readlane(__float_as_int(x), 63));
}

// Full-wave float sum via DPP (0-fill on invalid lanes = add identity).
__device__ __forceinline__ float wave_fsum_dpp(float x) {
#define DPPA_(ctrl) { int t_ = __builtin_amdgcn_update_dpp(                  \
      0, __float_as_int(x), (ctrl), 0xf, 0xf, true);                         \
    x += __int_as_float(t_); }
  DPPA_(0x111) DPPA_(0x112) DPPA_(0x114) DPPA_(0x118)
  DPPA_(0x142) DPPA_(0x143)
#undef DPPA_
  return __int_as_float(__builtin_amdgcn_readlane(__float_as_int(x), 63));
}

// wave-max of biased f32 exponents of (a, i0) via DPP reduce (R10-validated).
__device__ __forceinline__ int wave_max_bexp(float a, float i0) {
  int e  = (int)((__float_as_uint(a)  >> 23) & 0xffu);
  int e2 = (int)((__float_as_uint(i0) >> 23) & 0xffu);
  e = max(e, e2);
  int t;
  t = __builtin_amdgcn_update_dpp(e, e, 0x111, 0xf, 0xf, false); e = max(e, t);
  t = __builtin_amdgcn_update_dpp(e, e, 0x112, 0xf, 0xf, false); e = max(e, t);
  t = __builtin_amdgcn_update_dpp(e, e, 0x114, 0xf, 0xf, false); e = max(e, t);
  t = __builtin_amdgcn_update_dpp(e, e, 0x118, 0xf, 0xf, false); e = max(e, t);
  t = __builtin_amdgcn_update_dpp(e, e, 0x142, 0xf, 0xf, false); e = max(e, t);
  t = __builtin_amdgcn_update_dpp(e, e, 0x143, 0xf, 0xf, false); e = max(e, t);
  return __builtin_amdgcn_readlane(e, 63);
}

// ---------------------------------------------------------------------------
// K1: persistent-grid wave-per-row softmax (2048 blocks, 32 waves/CU) with
//     DPP reductions (R13-verified: ~40 us, at the cold-HBM floor). Emits
//     LINEAR probs in diagonal-major layout:
//       pk[b][t+u][u] = (.x = pll[t][u-1], .y = pbl[t][u])
//       col0[b][t+1]  = (.x = pbl[t][0],   .y = pll[t][0])
// ---------------------------------------------------------------------------
__global__ __launch_bounds__(256) void k1_linsoftmax(
    const float* __restrict__ acts, const int* __restrict__ labels,
    const int* __restrict__ label_lens,
    float2* __restrict__ pack, float2* __restrict__ col0, int* __restrict__ cnt) {
  const int lane = threadIdx.x & 63;
  const int wid  = blockIdx.x * 4 + (threadIdx.x >> 6);
  if (wid == 0 && lane == 0) *cnt = 0;             // k2's completion counter

  for (int row = wid; row < ROWS_; row += NWAVES_) {
    const int b   = row / (T_ * U1_);
    const int rem = row - b * (T_ * U1_);
    const int t   = rem / U1_;
    const int u   = rem - t * U1_;
    const float* __restrict__ p = acts + (size_t)row * V_;

    // hoisted label-path loads (lane 0 only)
    int ll_ = 0; float labv = 0.0f;
    if (lane == 0 && u < U_) {
      ll_  = label_lens[b];
      labv = p[labels[b * U_ + u]];                // in [1, V)
    }

    f32x4 v0 = *(const f32x4*)(p +   0 + lane * 4);
    f32x4 v1 = *(const f32x4*)(p + 256 + lane * 4);
    f32x4 v2 = *(const f32x4*)(p + 512 + lane * 4);
    f32x4 v3 = *(const f32x4*)(p + 768 + lane * 4);

    float ml = fmaxf(fmaxf(fmaxf(v0.x, v0.y), fmaxf(v0.z, v0.w)),
               fmaxf(fmaxf(fmaxf(v1.x, v1.y), fmaxf(v1.z, v1.w)),
               fmaxf(fmaxf(fmaxf(v2.x, v2.y), fmaxf(v2.z, v2.w)),
                     fmaxf(fmaxf(v3.x, v3.y), fmaxf(v3.z, v3.w)))));
    float m = wave_fmax_dpp(ml);

    float e00 = __expf(v0.x - m);                  // lane 0 holds exp(p[0]-m)
    float sl = e00          + __expf(v0.y - m) + __expf(v0.z - m) + __expf(v0.w - m)
             + __expf(v1.x - m) + __expf(v1.y - m) + __expf(v1.z - m) + __expf(v1.w - m)
             + __expf(v2.x - m) + __expf(v2.y - m) + __expf(v2.z - m) + __expf(v2.w - m)
             + __expf(v3.x - m) + __expf(v3.y - m) + __expf(v3.z - m) + __expf(v3.w - m);
    float s = wave_fsum_dpp(sl);

    if (lane == 0) {
      float rs = 1.0f / s;
      float pb = e00 * rs;                         // linear blank prob
      float2* pk = pack + (size_t)b * PACKB_;
      if (u == 0) {
        float pl0 = __expf(labv - m) * rs;         // u=0 < ll_ always (ll_ >= 32)
        col0[b * COL0N_ + (t + 1)] = make_float2(pb, pl0);
        pk[(size_t)(t + 1) * DS_ + 1].x = pl0;
      } else {
        pk[(size_t)(t + u) * DS_ + u].y = pb;
        if (u < U_) {
          float plv = (u < ll_) ? (__expf(labv - m) * rs) : 0.0f;
          pk[(size_t)(t + u + 1) * DS_ + (u + 1)].x = plv;
        }
      }
    }
  }
}

// ---------------------------------------------------------------------------
// K2: LDS-staged f32 probability-domain DP (fix for R13-measured latency
//     bound: VALUBusy 0.49%, lone wave eating L2/L3 round trips). 8 blocks x
//     256: 4 waves bulk-stage the batch pack (118 KB) + col0 into LDS with
//     coalesced float4 loads, then wave 0 runs the R11-verified DP against
//     LDS (ds latency covered by the existing 16-deep double buffer).
// ---------------------------------------------------------------------------
__global__ __launch_bounds__(256) void k2_alpha(
    const float2* __restrict__ pack, const float2* __restrict__ col0,
    const int* __restrict__ act_lens, const int* __restrict__ label_lens,
    float* __restrict__ costs, int* __restrict__ cnt, float* __restrict__ out) {
  __shared__ float2 pk_s[PACKB_];                  // 118,272 B
  __shared__ float2 c0_s[COL0N_];                  // 1,792 B
  const int b = (int)blockIdx.x;

  {  // stage: flat float4 copy, 4 waves in parallel (PACKB_*2 % 4 == 0)
    const f32x4* src = (const f32x4*)(pack + (size_t)b * PACKB_);
    f32x4* dst = (f32x4*)pk_s;
    #pragma unroll
    for (int k = 0; k < 29; ++k) {                 // 29*256 = 7424 >= 7392
      int i = k * 256 + (int)threadIdx.x;
      if (i < PACKB_ / 2) dst[i] = src[i];
    }
    const f32x4* cs = (const f32x4*)(col0 + (size_t)b * COL0N_);
    f32x4* cd = (f32x4*)c0_s;
    if (threadIdx.x < COL0N_ / 2) cd[threadIdx.x] = cs[threadIdx.x];
  }
  __syncthreads();
  if (threadIdx.x >= 64) return;

  const int l  = (int)threadIdx.x;                 // 0..63
  const int tl = act_lens[b] - 1;                  // in [63,127]
  const int ll = label_lens[b];                    // in [32,64]
  const int u  = l + 1;
  const int tcap = (u == ll) ? tl : 0x7fffffff;    // capture when t_ == tcap

  const float2* __restrict__ pku = pk_s + u;       // +DS_ per diag
  const float2* __restrict__ c0  = c0_s;

  float a = 0.0f;
  float i0 = (l == 0) ? 1.0f : 0.0f;               // alpha0 side-chain (lane 0)
  float fin = 0.0f, pbc = 0.0f;
  int   S = 0, Ecap = 0;
  int   t_ = -u;                                   // becomes dc-u after ++ in step

  float2 pA[16], pB[16], cA[16], cB[16];

#define LOADP(P, C, DB) do {                                             \
    const float2* q_ = pku + (size_t)(DB) * DS_;                         \
    _Pragma("unroll")                                                    \
    for (int j = 0; j < 16; ++j) (P)[j] = q_[(size_t)j * DS_];           \
    _Pragma("unroll")                                                    \
    for (int j = 0; j < 16; ++j) {                                       \
      float2 cv_ = c0[(DB) + j];                                         \
      bool ok_ = ((DB) + j) <= T_;            /* dc-1 in [0,127] */      \
      (C)[j].x = ok_ ? cv_.x : 0.0f;                                     \
      (C)[j].y = ok_ ? cv_.y : 0.0f;                                     \
    }                                                                    \
  } while (0)

#define RENORM() do {                                                    \
    int eS_ = wave_max_bexp(a, i0);                                      \
    int sh_ = min(167 - eS_, 126);     /* target biased exp 167 = 2^40 */\
    S += sh_;                                                            \
    float sc_ = ldexpf(1.0f, sh_);                                       \
    a *= sc_; i0 *= sc_;                                                 \
  } while (0)

#define COMPUTE8(P, C, JO) do {                                          \
    _Pragma("unroll")                                                    \
    for (int jj = 0; jj < 8; ++jj) {                                     \
      const int j = (JO) + jj;                                           \
      t_ += 1;                                                           \
      float shin = shr1_f32(a);                                          \
      float inj  = i0 * (C)[j].y;                                        \
      float anew = fmaf(a, pbc, fmaf(shin, (P)[j].x, inj));              \
      bool valid = ((unsigned)t_ < (unsigned)T_);                        \
      a = valid ? anew : 0.0f;            /* kills pad garbage/NaN */    \
      bool cap = (t_ == tcap);                                           \
      fin  = cap ? a : fin;                                              \
      Ecap = cap ? S : Ecap;                                             \
      i0 *= (C)[j].x;                                                    \
      pbc = (P)[j].y;                                                    \
    }                                                                    \
  } while (0)

  LOADP(pA, cA, 1);                                // block 0: dc = 1..16
  #pragma unroll 1
  for (int it = 0; it < 12; it += 2) {             // 6 iters x 32 steps = 192
    LOADP(pB, cB, 16 * it + 17);                   // odd block
    if (it > 0) RENORM();
    COMPUTE8(pA, cA, 0);
    RENORM();
    COMPUTE8(pA, cA, 8);
    if (it < 10) LOADP(pA, cA, 16 * it + 33);      // next even block (max diag 208 < 224)
    RENORM();
    COMPUTE8(pB, cB, 0);
    RENORM();
    COMPUTE8(pB, cB, 8);
  }
#undef LOADP
#undef RENORM
#undef COMPUTE8

  if (u == ll) {                                   // exactly one lane (ll in [32,64])
    float pblast = pk_s[(size_t)(tl + ll) * DS_ + ll].y;   // pbl[tl][ll]
    float lg = __log2f(fin) - (float)Ecap + __log2f(pblast);
    costs[b] = -lg * LN2F;
  }

  // last block to arrive sums the 8 costs (deterministic: single writer)
  __threadfence();
  if (l == 0) {
    int old = atomicAdd(cnt, 1);
    if (old == B_ - 1) {
      __threadfence();
      volatile const float* vc = costs;
      float s = 0.0f;
      #pragma unroll
      for (int i = 0; i < B_; ++i) s += vc[i];
      out[0] = s;
    }
  }
}

extern "C" void kernel_launch(void* const* d_in, const int* in_sizes, int n_in,
                              void* d_out, int out_size, void* d_ws, size_t ws_size,
                              hipStream_t stream) {
  const float* acts       = (const float*)d_in[0];
  const int*   labels     = (const int*)d_in[1];
  const int*   act_lens   = (const int*)d_in[2];
  const int*   label_lens = (const int*)d_in[3];

  float2* pack  = (float2*)d_ws;                     // B * 224*66 float2 = 946 KB
  float2* col0  = pack + (size_t)B_ * PACKB_;        // B * 224 float2
  float*  costs = (float*)(col0 + (size_t)B_ * COL0N_);
  int*    cnt   = (int*)(costs + B_);                // 1 int

  k1_linsoftmax<<<K1_BLOCKS_, 256, 0, stream>>>(acts, labels, label_lens, pack, col0, cnt);
  k2_alpha<<<B_, 256, 0, stream>>>(pack, col0, act_lens, label_lens, costs, cnt, (float*)d_out);
}

// Round 15
// 60.668 us; speedup vs baseline: 4.5014x; 1.0219x over previous
//
#include <hip/hip_runtime.h>

#define LN2F 0.6931471805599453f

// Problem constants (from setup_inputs: B=8, T=128, U=64, V=1024)
#define B_   8
#define T_   128
#define U_   64
#define U1_  65
#define V_   1024
#define ROWS_ (B_*T_*U1_)       // 66560
#define NDIAG_ 224              // diag index g=t+u in [0,192]; padded (DP reads to 208)
#define DS_    66               // float2 slots per diagonal (i = u in [1,64] used)
#define PACKB_ (NDIAG_*DS_)     // float2 per batch = 14784
#define COL0N_ 224
#define NWAVES_ 8192            // persistent k1: 2048 blocks * 4 waves (8/CU, 32 waves/CU)
#define K1_BLOCKS_ 2048

typedef float f32x4 __attribute__((ext_vector_type(4)));

// lane l <- lane l-1; lane 0 <- 0.0 (DPP wave_shr:1, bound_ctrl=1). One VALU op.
__device__ __forceinline__ float shr1_f32(float x) {
  return __int_as_float(__builtin_amdgcn_update_dpp(
      0, __float_as_int(x), 0x138, 0xf, 0xf, true));
}

// Full-wave float max via DPP (VALU pipe only; no DS traffic). R13-verified.
__device__ __forceinline__ float wave_fmax_dpp(float x) {
#define DPPM_(ctrl) { int t_ = __builtin_amdgcn_update_dpp(                  \
      __float_as_int(x), __float_as_int(x), (ctrl), 0xf, 0xf, false);        \
    x = fmaxf(x, __int_as_float(t_)); }
  DPPM_(0x111) DPPM_(0x112) DPPM_(0x114) DPPM_(0x118)   // row_shr 1,2,4,8
  DPPM_(0x142) DPPM_(0x143)                             // row_bcast 15,31
#undef DPPM_
  return __int_as_float(__builtin_amdgcn_readlane(__float_as_int(x), 63));
}

// Full-wave float sum via DPP (0-fill on invalid lanes = add identity).
__device__ __forceinline__ float wave_fsum_dpp(float x) {
#define DPPA_(ctrl) { int t_ = __builtin_amdgcn_update_dpp(                  \
      0, __float_as_int(x), (ctrl), 0xf, 0xf, true);                         \
    x += __int_as_float(t_); }
  DPPA_(0x111) DPPA_(0x112) DPPA_(0x114) DPPA_(0x118)
  DPPA_(0x142) DPPA_(0x143)
#undef DPPA_
  return __int_as_float(__builtin_amdgcn_readlane(__float_as_int(x), 63));
}

// wave-max of biased f32 exponents of (a, i0) via DPP reduce (R10-validated).
__device__ __forceinline__ int wave_max_bexp(float a, float i0) {
  int e  = (int)((__float_as_uint(a)  >> 23) & 0xffu);
  int e2 = (int)((__float_as_uint(i0) >> 23) & 0xffu);
  e = max(e, e2);
  int t;
  t = __builtin_amdgcn_update_dpp(e, e, 0x111, 0xf, 0xf, false); e = max(e, t);
  t = __builtin_amdgcn_update_dpp(e, e, 0x112, 0xf, 0xf, false); e = max(e, t);
  t = __builtin_amdgcn_update_dpp(e, e, 0x114, 0xf, 0xf, false); e = max(e, t);
  t = __builtin_amdgcn_update_dpp(e, e, 0x118, 0xf, 0xf, false); e = max(e, t);
  t = __builtin_amdgcn_update_dpp(e, e, 0x142, 0xf, 0xf, false); e = max(e, t);
  t = __builtin_amdgcn_update_dpp(e, e, 0x143, 0xf, 0xf, false); e = max(e, t);
  return __builtin_amdgcn_readlane(e, 63);
}

// ---------------------------------------------------------------------------
// K1: persistent-grid wave-per-row softmax (2048 blocks, 32 waves/CU) with
//     DPP reductions (R13-measured: ~40 us, at the cold-HBM floor). Emits
//     LINEAR probs in diagonal-major layout:
//       pk[b][t+u][u] = (.x = pll[t][u-1], .y = pbl[t][u])
//       col0[b][t+1]  = (.x = pbl[t][0],   .y = pll[t][0])
// ---------------------------------------------------------------------------
__global__ __launch_bounds__(256) void k1_linsoftmax(
    const float* __restrict__ acts, const int* __restrict__ labels,
    const int* __restrict__ label_lens,
    float2* __restrict__ pack, float2* __restrict__ col0, int* __restrict__ cnt) {
  const int lane = threadIdx.x & 63;
  const int wid  = blockIdx.x * 4 + (threadIdx.x >> 6);
  if (wid == 0 && lane == 0) *cnt = 0;             // k2's completion counter

  for (int row = wid; row < ROWS_; row += NWAVES_) {
    const int b   = row / (T_ * U1_);
    const int rem = row - b * (T_ * U1_);
    const int t   = rem / U1_;
    const int u   = rem - t * U1_;
    const float* __restrict__ p = acts + (size_t)row * V_;

    // hoisted label-path loads (lane 0 only)
    int ll_ = 0; float labv = 0.0f;
    if (lane == 0 && u < U_) {
      ll_  = label_lens[b];
      labv = p[labels[b * U_ + u]];                // in [1, V)
    }

    f32x4 v0 = *(const f32x4*)(p +   0 + lane * 4);
    f32x4 v1 = *(const f32x4*)(p + 256 + lane * 4);
    f32x4 v2 = *(const f32x4*)(p + 512 + lane * 4);
    f32x4 v3 = *(const f32x4*)(p + 768 + lane * 4);

    float ml = fmaxf(fmaxf(fmaxf(v0.x, v0.y), fmaxf(v0.z, v0.w)),
               fmaxf(fmaxf(fmaxf(v1.x, v1.y), fmaxf(v1.z, v1.w)),
               fmaxf(fmaxf(fmaxf(v2.x, v2.y), fmaxf(v2.z, v2.w)),
                     fmaxf(fmaxf(v3.x, v3.y), fmaxf(v3.z, v3.w)))));
    float m = wave_fmax_dpp(ml);

    float e00 = __expf(v0.x - m);                  // lane 0 holds exp(p[0]-m)
    float sl = e00          + __expf(v0.y - m) + __expf(v0.z - m) + __expf(v0.w - m)
             + __expf(v1.x - m) + __expf(v1.y - m) + __expf(v1.z - m) + __expf(v1.w - m)
             + __expf(v2.x - m) + __expf(v2.y - m) + __expf(v2.z - m) + __expf(v2.w - m)
             + __expf(v3.x - m) + __expf(v3.y - m) + __expf(v3.z - m) + __expf(v3.w - m);
    float s = wave_fsum_dpp(sl);

    if (lane == 0) {
      float rs = 1.0f / s;
      float pb = e00 * rs;                         // linear blank prob
      float2* pk = pack + (size_t)b * PACKB_;
      if (u == 0) {
        float pl0 = __expf(labv - m) * rs;         // u=0 < ll_ always (ll_ >= 32)
        col0[b * COL0N_ + (t + 1)] = make_float2(pb, pl0);
        pk[(size_t)(t + 1) * DS_ + 1].x = pl0;
      } else {
        pk[(size_t)(t + u) * DS_ + u].y = pb;
        if (u < U_) {
          float plv = (u < ll_) ? (__expf(labv - m) * rs) : 0.0f;
          pk[(size_t)(t + u + 1) * DS_ + (u + 1)].x = plv;
        }
      }
    }
  }
}

// ---------------------------------------------------------------------------
// K2: R11's f32 probability-domain diagonal DP, global reads, 8 blocks x 64
//     (R13-measured: 9.6 us; beats LDS staging for a single consumer wave
//     because the 16-deep prefetch overlaps cold-fetch latency with compute).
// ---------------------------------------------------------------------------
__global__ __launch_bounds__(64) void k2_alpha(
    const float2* __restrict__ pack, const float2* __restrict__ col0,
    const int* __restrict__ act_lens, const int* __restrict__ label_lens,
    float* __restrict__ costs, int* __restrict__ cnt, float* __restrict__ out) {
  const int b  = (int)blockIdx.x;
  const int l  = (int)threadIdx.x;                 // 0..63
  const int tl = act_lens[b] - 1;                  // in [63,127]
  const int ll = label_lens[b];                    // in [32,64]
  const int u  = l + 1;
  const int tcap = (u == ll) ? tl : 0x7fffffff;    // capture when t_ == tcap

  const float2* __restrict__ pku = pack + (size_t)b * PACKB_ + u;   // +DS_ per diag
  const float2* __restrict__ c0  = col0 + (size_t)b * COL0N_;

  float a = 0.0f;
  float i0 = (l == 0) ? 1.0f : 0.0f;               // alpha0 side-chain (lane 0)
  float fin = 0.0f, pbc = 0.0f;
  int   S = 0, Ecap = 0;
  int   t_ = -u;                                   // becomes dc-u after ++ in step

  float2 pA[16], pB[16], cA[16], cB[16];

#define LOADP(P, C, DB) do {                                             \
    const float2* q_ = pku + (size_t)(DB) * DS_;                         \
    _Pragma("unroll")                                                    \
    for (int j = 0; j < 16; ++j) (P)[j] = q_[(size_t)j * DS_];           \
    _Pragma("unroll")                                                    \
    for (int j = 0; j < 16; ++j) {                                       \
      float2 cv_ = c0[(DB) + j];                                         \
      bool ok_ = ((DB) + j) <= T_;            /* dc-1 in [0,127] */      \
      (C)[j].x = ok_ ? cv_.x : 0.0f;                                     \
      (C)[j].y = ok_ ? cv_.y : 0.0f;                                     \
    }                                                                    \
  } while (0)

#define RENORM() do {                                                    \
    int eS_ = wave_max_bexp(a, i0);                                      \
    int sh_ = min(167 - eS_, 126);     /* target biased exp 167 = 2^40 */\
    S += sh_;                                                            \
    float sc_ = ldexpf(1.0f, sh_);                                       \
    a *= sc_; i0 *= sc_;                                                 \
  } while (0)

#define COMPUTE8(P, C, JO) do {                                          \
    _Pragma("unroll")                                                    \
    for (int jj = 0; jj < 8; ++jj) {                                     \
      const int j = (JO) + jj;                                           \
      t_ += 1;                                                           \
      float shin = shr1_f32(a);                                          \
      float inj  = i0 * (C)[j].y;                                        \
      float anew = fmaf(a, pbc, fmaf(shin, (P)[j].x, inj));              \
      bool valid = ((unsigned)t_ < (unsigned)T_);                        \
      a = valid ? anew : 0.0f;            /* kills pad garbage/NaN */    \
      bool cap = (t_ == tcap);                                           \
      fin  = cap ? a : fin;                                              \
      Ecap = cap ? S : Ecap;                                             \
      i0 *= (C)[j].x;                                                    \
      pbc = (P)[j].y;                                                    \
    }                                                                    \
  } while (0)

  LOADP(pA, cA, 1);                                // block 0: dc = 1..16
  #pragma unroll 1
  for (int it = 0; it < 12; it += 2) {             // 6 iters x 32 steps = 192
    LOADP(pB, cB, 16 * it + 17);                   // odd block
    if (it > 0) RENORM();
    COMPUTE8(pA, cA, 0);
    RENORM();
    COMPUTE8(pA, cA, 8);
    if (it < 10) LOADP(pA, cA, 16 * it + 33);      // next even block (max diag 208 < 224)
    RENORM();
    COMPUTE8(pB, cB, 0);
    RENORM();
    COMPUTE8(pB, cB, 8);
  }
#undef LOADP
#undef RENORM
#undef COMPUTE8

  if (u == ll) {                                   // exactly one lane (ll in [32,64])
    float pblast = pack[(size_t)b * PACKB_ + (size_t)(tl + ll) * DS_ + ll].y;  // pbl[tl][ll]
    float lg = __log2f(fin) - (float)Ecap + __log2f(pblast);
    costs[b] = -lg * LN2F;
  }

  // last block to arrive sums the 8 costs (deterministic: single writer)
  __threadfence();
  if (l == 0) {
    int old = atomicAdd(cnt, 1);
    if (old == B_ - 1) {
      __threadfence();
      volatile const float* vc = costs;
      float s = 0.0f;
      #pragma unroll
      for (int i = 0; i < B_; ++i) s += vc[i];
      out[0] = s;
    }
  }
}

extern "C" void kernel_launch(void* const* d_in, const int* in_sizes, int n_in,
                              void* d_out, int out_size, void* d_ws, size_t ws_size,
                              hipStream_t stream) {
  const float* acts       = (const float*)d_in[0];
  const int*   labels     = (const int*)d_in[1];
  const int*   act_lens   = (const int*)d_in[2];
  const int*   label_lens = (const int*)d_in[3];

  float2* pack  = (float2*)d_ws;                     // B * 224*66 float2 = 946 KB
  float2* col0  = pack + (size_t)B_ * PACKB_;        // B * 224 float2
  float*  costs = (float*)(col0 + (size_t)B_ * COL0N_);
  int*    cnt   = (int*)(costs + B_);                // 1 int

  k1_linsoftmax<<<K1_BLOCKS_, 256, 0, stream>>>(acts, labels, label_lens, pack, col0, cnt);
  k2_alpha<<<B_, 64, 0, stream>>>(pack, col0, act_lens, label_lens, costs, cnt, (float*)d_out);
}

// Round 16
// 57.140 us; speedup vs baseline: 4.7794x; 1.0617x over previous
//
#include <hip/hip_runtime.h>

#define LN2F 0.6931471805599453f

// Problem constants (from setup_inputs: B=8, T=128, U=64, V=1024)
#define B_   8
#define T_   128
#define U_   64
#define U1_  65
#define V_   1024
#define ROWS_ (B_*T_*U1_)       // 66560
#define NDIAG_ 224              // diag index g=t+u in [0,192]; padded
#define DS_    66               // float2 slots per diagonal (i = u in [1,64] used)
#define PACKB_ (NDIAG_*DS_)     // float2 per batch = 14784
#define COL0N_ 224
#define NWAVES_ 8192            // persistent k1: 2048 blocks * 4 waves (8/CU, 32 waves/CU)
#define K1_BLOCKS_ 2048

typedef float f32x4 __attribute__((ext_vector_type(4)));

// lane l <- lane l-1; lane 0 <- 0.0 (DPP wave_shr:1, bound_ctrl=1). One VALU op.
__device__ __forceinline__ float shr1_f32(float x) {
  return __int_as_float(__builtin_amdgcn_update_dpp(
      0, __float_as_int(x), 0x138, 0xf, 0xf, true));
}

// Full-wave float max via DPP (VALU pipe only; no DS traffic). R13-verified.
__device__ __forceinline__ float wave_fmax_dpp(float x) {
#define DPPM_(ctrl) { int t_ = __builtin_amdgcn_update_dpp(                  \
      __float_as_int(x), __float_as_int(x), (ctrl), 0xf, 0xf, false);        \
    x = fmaxf(x, __int_as_float(t_)); }
  DPPM_(0x111) DPPM_(0x112) DPPM_(0x114) DPPM_(0x118)   // row_shr 1,2,4,8
  DPPM_(0x142) DPPM_(0x143)                             // row_bcast 15,31
#undef DPPM_
  return __int_as_float(__builtin_amdgcn_readlane(__float_as_int(x), 63));
}

// Full-wave float sum via DPP (0-fill on invalid lanes = add identity).
__device__ __forceinline__ float wave_fsum_dpp(float x) {
#define DPPA_(ctrl) { int t_ = __builtin_amdgcn_update_dpp(                  \
      0, __float_as_int(x), (ctrl), 0xf, 0xf, true);                         \
    x += __int_as_float(t_); }
  DPPA_(0x111) DPPA_(0x112) DPPA_(0x114) DPPA_(0x118)
  DPPA_(0x142) DPPA_(0x143)
#undef DPPA_
  return __int_as_float(__builtin_amdgcn_readlane(__float_as_int(x), 63));
}

// wave-max of biased f32 exponents of (a, i0) via DPP reduce (R10-validated).
__device__ __forceinline__ int wave_max_bexp(float a, float i0) {
  int e  = (int)((__float_as_uint(a)  >> 23) & 0xffu);
  int e2 = (int)((__float_as_uint(i0) >> 23) & 0xffu);
  e = max(e, e2);
  int t;
  t = __builtin_amdgcn_update_dpp(e, e, 0x111, 0xf, 0xf, false); e = max(e, t);
  t = __builtin_amdgcn_update_dpp(e, e, 0x112, 0xf, 0xf, false); e = max(e, t);
  t = __builtin_amdgcn_update_dpp(e, e, 0x114, 0xf, 0xf, false); e = max(e, t);
  t = __builtin_amdgcn_update_dpp(e, e, 0x118, 0xf, 0xf, false); e = max(e, t);
  t = __builtin_amdgcn_update_dpp(e, e, 0x142, 0xf, 0xf, false); e = max(e, t);
  t = __builtin_amdgcn_update_dpp(e, e, 0x143, 0xf, 0xf, false); e = max(e, t);
  return __builtin_amdgcn_readlane(e, 63);
}

// ---------------------------------------------------------------------------
// K1: persistent-grid wave-per-row softmax (2048 blocks, 32 waves/CU) with
//     DPP reductions (R13-measured: ~40 us, at the cold-HBM floor). Emits
//     LINEAR probs in diagonal-major layout:
//       pk[b][t+u][u] = (.x = pll[t][u-1], .y = pbl[t][u])
//       col0[b][t+1]  = (.x = pbl[t][0],   .y = pll[t][0])
// ---------------------------------------------------------------------------
__global__ __launch_bounds__(256) void k1_linsoftmax(
    const float* __restrict__ acts, const int* __restrict__ labels,
    const int* __restrict__ label_lens,
    float2* __restrict__ pack, float2* __restrict__ col0, int* __restrict__ cnt) {
  const int lane = threadIdx.x & 63;
  const int wid  = blockIdx.x * 4 + (threadIdx.x >> 6);
  if (wid == 0 && lane == 0) *cnt = 0;             // k2's completion counter

  for (int row = wid; row < ROWS_; row += NWAVES_) {
    const int b   = row / (T_ * U1_);
    const int rem = row - b * (T_ * U1_);
    const int t   = rem / U1_;
    const int u   = rem - t * U1_;
    const float* __restrict__ p = acts + (size_t)row * V_;

    // hoisted label-path loads (lane 0 only)
    int ll_ = 0; float labv = 0.0f;
    if (lane == 0 && u < U_) {
      ll_  = label_lens[b];
      labv = p[labels[b * U_ + u]];                // in [1, V)
    }

    f32x4 v0 = *(const f32x4*)(p +   0 + lane * 4);
    f32x4 v1 = *(const f32x4*)(p + 256 + lane * 4);
    f32x4 v2 = *(const f32x4*)(p + 512 + lane * 4);
    f32x4 v3 = *(const f32x4*)(p + 768 + lane * 4);

    float ml = fmaxf(fmaxf(fmaxf(v0.x, v0.y), fmaxf(v0.z, v0.w)),
               fmaxf(fmaxf(fmaxf(v1.x, v1.y), fmaxf(v1.z, v1.w)),
               fmaxf(fmaxf(fmaxf(v2.x, v2.y), fmaxf(v2.z, v2.w)),
                     fmaxf(fmaxf(v3.x, v3.y), fmaxf(v3.z, v3.w)))));
    float m = wave_fmax_dpp(ml);

    float e00 = __expf(v0.x - m);                  // lane 0 holds exp(p[0]-m)
    float sl = e00          + __expf(v0.y - m) + __expf(v0.z - m) + __expf(v0.w - m)
             + __expf(v1.x - m) + __expf(v1.y - m) + __expf(v1.z - m) + __expf(v1.w - m)
             + __expf(v2.x - m) + __expf(v2.y - m) + __expf(v2.z - m) + __expf(v2.w - m)
             + __expf(v3.x - m) + __expf(v3.y - m) + __expf(v3.z - m) + __expf(v3.w - m);
    float s = wave_fsum_dpp(sl);

    if (lane == 0) {
      float rs = 1.0f / s;
      float pb = e00 * rs;                         // linear blank prob
      float2* pk = pack + (size_t)b * PACKB_;
      if (u == 0) {
        float pl0 = __expf(labv - m) * rs;         // u=0 < ll_ always (ll_ >= 32)
        col0[b * COL0N_ + (t + 1)] = make_float2(pb, pl0);
        pk[(size_t)(t + 1) * DS_ + 1].x = pl0;
      } else {
        pk[(size_t)(t + u) * DS_ + u].y = pb;
        if (u < U_) {
          float plv = (u < ll_) ? (__expf(labv - m) * rs) : 0.0f;
          pk[(size_t)(t + u + 1) * DS_ + (u + 1)].x = plv;
        }
      }
    }
  }
}

// ---------------------------------------------------------------------------
// K2: f32 probability-domain diagonal DP with DEEP prefetch (fix for the
//     R15-measured cold-latency bound: 18 us cold vs 9.6 warm). col0 lives
//     in LDS (lgkm counter; tail pre-zeroed), so each 16-step burst is only
//     16 vmem ops; 4 named buffer sets give lookahead-3 (48 steps ~ 1200 cyc
//     of compute cover, 48 outstanding vmem <= 63 cap).
// ---------------------------------------------------------------------------
__global__ __launch_bounds__(64) void k2_alpha(
    const float2* __restrict__ pack, const float2* __restrict__ col0,
    const int* __restrict__ act_lens, const int* __restrict__ label_lens,
    float* __restrict__ costs, int* __restrict__ cnt, float* __restrict__ out) {
  __shared__ float2 c0_s[COL0N_];
  const int b  = (int)blockIdx.x;
  const int l  = (int)threadIdx.x;                 // 0..63

  {  // stage col0 into LDS; zero unwritten tail (valid indices are 1..128)
    const float2* src = col0 + (size_t)b * COL0N_;
    #pragma unroll
    for (int k = 0; k < 4; ++k) {
      int i = k * 64 + l;                          // 0..255; COL0N_=224
      if (i < COL0N_) {
        float2 v = src[i];
        bool ok = (i >= 1) && (i <= T_);
        c0_s[i] = ok ? v : make_float2(0.0f, 0.0f);
      }
    }
  }
  // single wave: no barrier needed; compiler orders vm/ds counters

  const int tl = act_lens[b] - 1;                  // in [63,127]
  const int ll = label_lens[b];                    // in [32,64]
  const int u  = l + 1;
  const int tcap = (u == ll) ? tl : 0x7fffffff;    // capture when t_ == tcap

  const float2* __restrict__ pku = pack + (size_t)b * PACKB_ + u;   // +DS_ per diag

  float a = 0.0f;
  float i0 = (l == 0) ? 1.0f : 0.0f;               // alpha0 side-chain (lane 0)
  float fin = 0.0f, pbc = 0.0f;
  int   S = 0, Ecap = 0;
  int   t_ = -u;                                   // becomes dc-u after ++ in step

  float2 pA[16], pB[16], pC[16], pD[16];
  float2 cA[16], cB[16], cC[16], cD[16];

#define LOADP(P, C, DB) do {                                             \
    const float2* q_ = pku + (size_t)(DB) * DS_;                         \
    _Pragma("unroll")                                                    \
    for (int j = 0; j < 16; ++j) (P)[j] = q_[(size_t)j * DS_];           \
    _Pragma("unroll")                                                    \
    for (int j = 0; j < 16; ++j) (C)[j] = c0_s[(DB) + j];                \
  } while (0)

#define RENORM() do {                                                    \
    int eS_ = wave_max_bexp(a, i0);                                      \
    int sh_ = min(167 - eS_, 126);     /* target biased exp 167 = 2^40 */\
    S += sh_;                                                            \
    float sc_ = ldexpf(1.0f, sh_);                                       \
    a *= sc_; i0 *= sc_;                                                 \
  } while (0)

#define COMPUTE8(P, C, JO) do {                                          \
    _Pragma("unroll")                                                    \
    for (int jj = 0; jj < 8; ++jj) {                                     \
      const int j = (JO) + jj;                                           \
      t_ += 1;                                                           \
      float shin = shr1_f32(a);                                          \
      float inj  = i0 * (C)[j].y;                                        \
      float anew = fmaf(a, pbc, fmaf(shin, (P)[j].x, inj));              \
      bool valid = ((unsigned)t_ < (unsigned)T_);                        \
      a = valid ? anew : 0.0f;            /* kills pad garbage/NaN */    \
      bool cap = (t_ == tcap);                                           \
      fin  = cap ? a : fin;                                              \
      Ecap = cap ? S : Ecap;                                             \
      i0 *= (C)[j].x;                                                    \
      pbc = (P)[j].y;                                                    \
    }                                                                    \
  } while (0)

  // prologue: 4 blocks in flight (dc = 1..64)
  LOADP(pA, cA, 1);
  LOADP(pB, cB, 17);
  LOADP(pC, cC, 33);
  LOADP(pD, cD, 49);

  #pragma unroll 1
  for (int it4 = 0; it4 < 3; ++it4) {              // 4 blocks of 16 steps per iter
    if (it4 > 0) RENORM();
    COMPUTE8(pA, cA, 0);
    RENORM();
    COMPUTE8(pA, cA, 8);
    if (it4 < 2) LOADP(pA, cA, 64 * it4 + 65);     // block +4 (lookahead 3)

    RENORM();
    COMPUTE8(pB, cB, 0);
    RENORM();
    COMPUTE8(pB, cB, 8);
    if (it4 < 2) LOADP(pB, cB, 64 * it4 + 81);

    RENORM();
    COMPUTE8(pC, cC, 0);
    RENORM();
    COMPUTE8(pC, cC, 8);
    if (it4 < 2) LOADP(pC, cC, 64 * it4 + 97);

    RENORM();
    COMPUTE8(pD, cD, 0);
    RENORM();
    COMPUTE8(pD, cD, 8);
    if (it4 < 2) LOADP(pD, cD, 64 * it4 + 113);
  }
#undef LOADP
#undef RENORM
#undef COMPUTE8

  if (u == ll) {                                   // exactly one lane (ll in [32,64])
    float pblast = pack[(size_t)b * PACKB_ + (size_t)(tl + ll) * DS_ + ll].y;  // pbl[tl][ll]
    float lg = __log2f(fin) - (float)Ecap + __log2f(pblast);
    costs[b] = -lg * LN2F;
  }

  // last block to arrive sums the 8 costs (deterministic: single writer)
  __threadfence();
  if (l == 0) {
    int old = atomicAdd(cnt, 1);
    if (old == B_ - 1) {
      __threadfence();
      volatile const float* vc = costs;
      float s = 0.0f;
      #pragma unroll
      for (int i = 0; i < B_; ++i) s += vc[i];
      out[0] = s;
    }
  }
}

extern "C" void kernel_launch(void* const* d_in, const int* in_sizes, int n_in,
                              void* d_out, int out_size, void* d_ws, size_t ws_size,
                              hipStream_t stream) {
  const float* acts       = (const float*)d_in[0];
  const int*   labels     = (const int*)d_in[1];
  const int*   act_lens   = (const int*)d_in[2];
  const int*   label_lens = (const int*)d_in[3];

  float2* pack  = (float2*)d_ws;                     // B * 224*66 float2 = 946 KB
  float2* col0  = pack + (size_t)B_ * PACKB_;        // B * 224 float2
  float*  costs = (float*)(col0 + (size_t)B_ * COL0N_);
  int*    cnt   = (int*)(costs + B_);                // 1 int

  k1_linsoftmax<<<K1_BLOCKS_, 256, 0, stream>>>(acts, labels, label_lens, pack, col0, cnt);
  k2_alpha<<<B_, 64, 0, stream>>>(pack, col0, act_lens, label_lens, costs, cnt, (float*)d_out);
}